// Round 1
// baseline (639.747 us; speedup 1.0000x reference)
//
#include <hip/hip_runtime.h>
#include <cmath>

typedef unsigned int uint32;
typedef __bf16 bf16;
typedef __bf16 bf16x8 __attribute__((ext_vector_type(8)));
typedef float f32x4 __attribute__((ext_vector_type(4)));

#define LVLS 10
#define TSIZE 65536
#define TMASK 65535u
#define PRIME2 2654435761u
#define PRIME3 805459861u

// ---- ws layout (bytes) ----
//   [0,      18432): W1t/W2t/W3t bf16 images (9216 elems)
//   [18432,  18472): dq[10] f32  (scale/127 per level)
//   [18496,  18536): scales[10] u32 (absmax bits, atomicMax target; memset 0)
//   [18560,  18560+2621440): uint8 table [10][65536][4], biased +128 (64B-aligned)
#define WOFF_W1 0
#define WOFF_W2 4096
#define WOFF_W3 8192
#define W_ELEMS 9216
#define DQ_OFF 18432
#define SC_OFF 18496
#define TAB_OFF_B 18560
#define TAB_ELEMS_F (LVLS * TSIZE * 4)   // f32 source elems
#define WS_NEEDED ((size_t)TAB_OFF_B + (size_t)TAB_ELEMS_F)

struct KParams { float resf[LVLS]; };

// ---------------- prep 1: per-level absmax ----------------
__global__ void scale_kernel(const float* __restrict__ tables, unsigned* __restrict__ scales) {
  int tid = blockIdx.x * 256 + threadIdx.x;
  int i4 = tid * 4;
  if (i4 >= TAB_ELEMS_F) return;
  float4 v = *(const float4*)(tables + i4);
  float m = fmaxf(fmaxf(fabsf(v.x), fabsf(v.y)), fmaxf(fabsf(v.z), fabsf(v.w)));
#pragma unroll
  for (int off = 32; off; off >>= 1) m = fmaxf(m, __shfl_xor(m, off, 64));
  if ((threadIdx.x & 63) == 0) {
    int l = i4 >> 18;  // 65536*4 = 2^18 elems per level; waves never straddle
    atomicMax(scales + l, __float_as_uint(m));
  }
}

// ---------------- prep 2: weight transpose + int8 quantize (biased +128) ----------------
__global__ void quant_kernel(const float* __restrict__ W1, const float* __restrict__ W2,
                             const float* __restrict__ W3, const float* __restrict__ tables,
                             char* __restrict__ ws8, int do_tab) {
  int tid = blockIdx.x * 256 + threadIdx.x;
  bf16* wsb = (bf16*)ws8;
  if (tid < W_ELEMS) {
    float v;
    if (tid < 4096) {
      int n = tid >> 6, k = tid & 63;
      v = (k < 40) ? W1[k * 64 + n] : 0.f;
    } else if (tid < 8192) {
      int t2 = tid - 4096; int n = t2 >> 6, k = t2 & 63;
      v = W2[k * 64 + n];
    } else {
      int t3 = tid - 8192; int n = t3 >> 6, k = t3 & 63;
      v = (n < 13) ? W3[k * 13 + n] : 0.f;
    }
    wsb[tid] = (bf16)v;
  }
  const unsigned* scales = (const unsigned*)(ws8 + SC_OFF);
  if (tid < LVLS) {
    float s = __uint_as_float(scales[tid]);
    ((float*)(ws8 + DQ_OFF))[tid] = s * (1.0f / 127.0f);
  }
  if (do_tab) {
    int i4 = tid * 4;
    if (i4 < TAB_ELEMS_F) {
      float4 v = *(const float4*)(tables + i4);
      int l = i4 >> 18;
      float s = __uint_as_float(scales[l]);
      float r = (s > 0.f) ? 127.f / s : 0.f;
      int q0 = (int)rintf(fminf(fmaxf(v.x * r, -127.f), 127.f)) + 128;
      int q1 = (int)rintf(fminf(fmaxf(v.y * r, -127.f), 127.f)) + 128;
      int q2 = (int)rintf(fminf(fmaxf(v.z * r, -127.f), 127.f)) + 128;
      int q3 = (int)rintf(fminf(fmaxf(v.w * r, -127.f), 127.f)) + 128;
      unsigned p = (q0 & 0xff) | ((q1 & 0xff) << 8) | ((q2 & 0xff) << 16) | ((q3 & 0xff) << 24);
      *(unsigned*)(ws8 + TAB_OFF_B + i4) = p;
    }
  }
}

// ---------------- device helpers ----------------
__device__ __forceinline__ float selu_f(float v) {
  float neg = 1.6732632423543772f * (__expf(v) - 1.0f);
  return 1.0507009873554805f * (v > 0.f ? v : neg);
}

// Hbuf: 256 rows x 128 B (stride 64 bf16), XOR-swizzled at 16B granularity so
// 16-lanes-read-16-rows-same-col (GEMM A-operand pattern) is conflict-free.
__device__ __forceinline__ bf16* hswz(bf16* Hb, int row, int cb) {
  return (bf16*)((char*)Hb + (row << 7) + (cb ^ ((row & 7) << 4)));
}

// One hidden-layer GEMM stage, split into two 32-col halves to keep peak
// register pressure <= ~90 (needed for 5 waves/SIMD). A-fragments are hoisted
// into registers BEFORE any H-write (half 0 writes would otherwise corrupt
// half 1's A reads, since H overwrites the input rows in-place).
__device__ __forceinline__ void gemm_stage(bf16* __restrict__ Hb, int w, int lr, int quad,
                                           const bf16* __restrict__ Bbase,
                                           const float* __restrict__ bvec) {
  bf16x8 Af[2][4];
#pragma unroll
  for (int ks = 0; ks < 2; ++ks)
#pragma unroll
    for (int ms = 0; ms < 4; ++ms)
      Af[ks][ms] = *(const bf16x8*)hswz(Hb, w * 64 + ms * 16 + lr, quad * 16 + ks * 64);
#pragma unroll
  for (int h = 0; h < 2; ++h) {
    f32x4 acc[4][2];
#pragma unroll
    for (int nt2 = 0; nt2 < 2; ++nt2) {
      float b = bvec[(h * 2 + nt2) * 16 + lr];
#pragma unroll
      for (int ms = 0; ms < 4; ++ms) {
        f32x4 a = {b, b, b, b};
        acc[ms][nt2] = a;
      }
    }
#pragma unroll
    for (int ks = 0; ks < 2; ++ks) {
      bf16x8 B0 = *(const bf16x8*)(Bbase + (h * 2 + 0) * 1024 + ks * 32);
      bf16x8 B1 = *(const bf16x8*)(Bbase + (h * 2 + 1) * 1024 + ks * 32);
#pragma unroll
      for (int ms = 0; ms < 4; ++ms) {
        acc[ms][0] = __builtin_amdgcn_mfma_f32_16x16x32_bf16(Af[ks][ms], B0, acc[ms][0], 0, 0, 0);
        acc[ms][1] = __builtin_amdgcn_mfma_f32_16x16x32_bf16(Af[ks][ms], B1, acc[ms][1], 0, 0, 0);
      }
    }
#pragma unroll
    for (int ms = 0; ms < 4; ++ms)
#pragma unroll
      for (int nt2 = 0; nt2 < 2; ++nt2)
#pragma unroll
        for (int r = 0; r < 4; ++r) {
          int row = w * 64 + quad * 4 + ms * 16 + r;
          *hswz(Hb, row, ((h * 2 + nt2) * 16 + lr) * 2) = (bf16)selu_f(acc[ms][nt2][r]);
        }
  }
}

// level offset (l<<16) folded into idx so gathers are a single uniform base.
#define CALC_IDX(L, IDX, F0, F1, F2)                                   \
  do {                                                                 \
    const float rs_ = kp.resf[(L)];                                    \
    float xs_ = px * rs_, ys_ = py * rs_, zs_ = pz * rs_;              \
    float bx_ = floorf(xs_), by_ = floorf(ys_), bz_ = floorf(zs_);     \
    (F0) = xs_ - bx_; (F1) = ys_ - by_; (F2) = zs_ - bz_;              \
    uint32 cx_ = (uint32)bx_, cy_ = (uint32)by_, cz_ = (uint32)bz_;    \
    uint32 hy0_ = cy_ * PRIME2, hy1_ = hy0_ + PRIME2;                  \
    uint32 hz0_ = cz_ * PRIME3, hz1_ = hz0_ + PRIME3;                  \
    uint32 cx1_ = cx_ + 1u;                                            \
    uint32 bse_ = (uint32)(L) << 16;                                   \
    (IDX)[0] = ((cx_ ^ hy0_ ^ hz0_) & TMASK) | bse_;                   \
    (IDX)[1] = ((cx_ ^ hy0_ ^ hz1_) & TMASK) | bse_;                   \
    (IDX)[2] = ((cx_ ^ hy1_ ^ hz0_) & TMASK) | bse_;                   \
    (IDX)[3] = ((cx_ ^ hy1_ ^ hz1_) & TMASK) | bse_;                   \
    (IDX)[4] = ((cx1_ ^ hy0_ ^ hz0_) & TMASK) | bse_;                  \
    (IDX)[5] = ((cx1_ ^ hy0_ ^ hz1_) & TMASK) | bse_;                  \
    (IDX)[6] = ((cx1_ ^ hy1_ ^ hz0_) & TMASK) | bse_;                  \
    (IDX)[7] = ((cx1_ ^ hy1_ ^ hz1_) & TMASK) | bse_;                  \
  } while (0)

// ---------------- fused encode + MLP ----------------
// 256 threads (4 waves), 256 points per block. LDS = 32768 B exactly ->
// 5 blocks/CU (160 KiB), up from 4 at stride-72. launch_bounds(256,5) caps
// unified VGPR at 102 so 5 waves/SIMD are actually resident.
template <bool TB>
__global__ __launch_bounds__(256, 5)
void ngp_fused(const float* __restrict__ x, const float* __restrict__ cr,
               const float* __restrict__ tables, const char* __restrict__ ws8,
               const float* __restrict__ b1, const float* __restrict__ b2,
               const float* __restrict__ b3, float* __restrict__ out,
               int N, KParams kp) {
  __shared__ __align__(16) bf16 Hbuf[256 * 64];
  const int tid = threadIdx.x;
  const int n = blockIdx.x * 256 + tid;
  const int ncl = (n < N) ? n : 0;

  const float px = x[ncl * 3 + 0];
  const float py = x[ncl * 3 + 1];
  const float pz = x[ncl * 3 + 2];
  const float crv = cr[ncl];
  const float* dq = (const float*)(ws8 + DQ_OFF);

  float feat[40];

  if constexpr (TB) {
    const unsigned* tb = (const unsigned*)(ws8 + TAB_OFF_B);
    // 2-deep software pipeline: issue level l+1's 8 gathers before consuming
    // level l's results -> compiler emits counted vmcnt, VMEM pipe stays fed.
    uint32 idx0[8];
    float pf0, pf1, pf2;
    CALC_IDX(0, idx0, pf0, pf1, pf2);
    unsigned qP[8];
#pragma unroll
    for (int c = 0; c < 8; ++c) qP[c] = tb[idx0[c]];
#pragma unroll
    for (int l = 0; l < LVLS; ++l) {
      unsigned qN[8];
      float nf0 = 0.f, nf1 = 0.f, nf2 = 0.f;
      if (l + 1 < LVLS) {
        uint32 idxN[8];
        CALC_IDX(l + 1, idxN, nf0, nf1, nf2);
#pragma unroll
        for (int c = 0; c < 8; ++c) qN[c] = tb[idxN[c]];
      }
      float fx = pf0, fy = pf1, fz = pf2;
      float wx1 = fx, wx0 = 1.f - fx, wy1 = fy, wy0 = 1.f - fy, wz1 = fz, wz0 = 1.f - fz;
      float wxy00 = wx0 * wy0, wxy01 = wx0 * wy1, wxy10 = wx1 * wy0, wxy11 = wx1 * wy1;
      float w8[8] = {wxy00 * wz0, wxy00 * wz1, wxy01 * wz0, wxy01 * wz1,
                     wxy10 * wz0, wxy10 * wz1, wxy11 * wz0, wxy11 * wz1};
      float a0 = 0.f, a1 = 0.f, a2 = 0.f, a3 = 0.f;
#pragma unroll
      for (int c = 0; c < 8; ++c) {
        // biased-ubyte unpack -> v_cvt_f32_ubyte{0..3}; the -128*sum(w) term
        // folds to -128 exactly (trilinear weights sum to 1).
        unsigned q = qP[c];
        float u0 = (float)(q & 0xffu);
        float u1 = (float)((q >> 8) & 0xffu);
        float u2 = (float)((q >> 16) & 0xffu);
        float u3 = (float)(q >> 24);
        a0 = fmaf(w8[c], u0, a0);
        a1 = fmaf(w8[c], u1, a1);
        a2 = fmaf(w8[c], u2, a2);
        a3 = fmaf(w8[c], u3, a3);
      }
      // l==0: erf(rsqrt(1e-12)) == 1.0f exactly -> skip the transcendental.
      float s = (l == 0) ? dq[0]
                         : erff(rsqrtf(fmaxf(4.0f * (float)l * crv, 1e-12f))) * dq[l];
      feat[0 * 10 + l] = (a0 - 128.f) * s;
      feat[1 * 10 + l] = (a1 - 128.f) * s;
      feat[2 * 10 + l] = (a2 - 128.f) * s;
      feat[3 * 10 + l] = (a3 - 128.f) * s;
      if (l + 1 < LVLS) {
#pragma unroll
        for (int c = 0; c < 8; ++c) qP[c] = qN[c];
        pf0 = nf0; pf1 = nf1; pf2 = nf2;
      }
    }
  } else {
    // f32 fallback (no ws room): unpipelined, matches original semantics.
#pragma unroll
    for (int l = 0; l < LVLS; ++l) {
      uint32 idx[8];
      float fx, fy, fz;
      CALC_IDX(l, idx, fx, fy, fz);
      const float4* tb4 = (const float4*)tables;  // idx already has l<<16 folded
      float f[8][4];
#pragma unroll
      for (int c = 0; c < 8; ++c) {
        float4 q = tb4[idx[c]];
        f[c][0] = q.x; f[c][1] = q.y; f[c][2] = q.z; f[c][3] = q.w;
      }
      float wx1 = fx, wx0 = 1.f - fx, wy1 = fy, wy0 = 1.f - fy, wz1 = fz, wz0 = 1.f - fz;
      float wxy00 = wx0 * wy0, wxy01 = wx0 * wy1, wxy10 = wx1 * wy0, wxy11 = wx1 * wy1;
      float w8[8] = {wxy00 * wz0, wxy00 * wz1, wxy01 * wz0, wxy01 * wz1,
                     wxy10 * wz0, wxy10 * wz1, wxy11 * wz0, wxy11 * wz1};
      float a0 = 0.f, a1 = 0.f, a2 = 0.f, a3 = 0.f;
#pragma unroll
      for (int c = 0; c < 8; ++c) {
        a0 = fmaf(w8[c], f[c][0], a0);
        a1 = fmaf(w8[c], f[c][1], a1);
        a2 = fmaf(w8[c], f[c][2], a2);
        a3 = fmaf(w8[c], f[c][3], a3);
      }
      float s = (l == 0) ? 1.0f : erff(rsqrtf(fmaxf(4.0f * (float)l * crv, 1e-12f)));
      feat[0 * 10 + l] = a0 * s;
      feat[1 * 10 + l] = a1 * s;
      feat[2 * 10 + l] = a2 * s;
      feat[3 * 10 + l] = a3 * s;
    }
  }

  {
#pragma unroll
    for (int c = 0; c < 5; ++c) {
      bf16x8 v;
#pragma unroll
      for (int j = 0; j < 8; ++j) v[j] = (bf16)feat[c * 8 + j];
      *(bf16x8*)hswz(Hbuf, tid, c * 16) = v;
    }
    bf16x8 z;
#pragma unroll
    for (int j = 0; j < 8; ++j) z[j] = (bf16)0.f;
    *(bf16x8*)hswz(Hbuf, tid, 80) = z;
    *(bf16x8*)hswz(Hbuf, tid, 96) = z;
    *(bf16x8*)hswz(Hbuf, tid, 112) = z;
  }
  __syncthreads();

  const int w = tid >> 6;
  const int lane = tid & 63;
  const int lr = lane & 15;
  const int quad = lane >> 4;
  const bf16* wsb = (const bf16*)ws8;

  gemm_stage(Hbuf, w, lr, quad, wsb + WOFF_W1 + lr * 64 + quad * 8, b1);
  __syncthreads();
  gemm_stage(Hbuf, w, lr, quad, wsb + WOFF_W2 + lr * 64 + quad * 8, b2);
  __syncthreads();

  // ---- stage 3 (64 -> 13) + LDS-staged coalesced output ----
  {
    float b3v = (lr < 13) ? b3[lr] : 0.f;
    f32x4 acc3[4];
#pragma unroll
    for (int ms = 0; ms < 4; ++ms) {
      f32x4 a = {b3v, b3v, b3v, b3v};
      acc3[ms] = a;
    }
    const bf16* B3b = wsb + WOFF_W3 + lr * 64 + quad * 8;
    bf16x8 B3[2];
    B3[0] = *(const bf16x8*)(B3b);
    B3[1] = *(const bf16x8*)(B3b + 32);
#pragma unroll
    for (int ks = 0; ks < 2; ++ks) {
      bf16x8 Af[4];
#pragma unroll
      for (int ms = 0; ms < 4; ++ms)
        Af[ms] = *(const bf16x8*)hswz(Hbuf, w * 64 + ms * 16 + lr, quad * 16 + ks * 64);
#pragma unroll
      for (int ms = 0; ms < 4; ++ms)
        acc3[ms] = __builtin_amdgcn_mfma_f32_16x16x32_bf16(Af[ms], B3[ks], acc3[ms], 0, 0, 0);
    }
    __syncthreads();  // done reading Hbuf; reuse it as f32 output stage
    float* Obuf = (float*)Hbuf;  // 256*13*4 = 13312 B <= 32768 B
#pragma unroll
    for (int ms = 0; ms < 4; ++ms)
#pragma unroll
      for (int r = 0; r < 4; ++r)
        if (lr < 13)
          Obuf[(w * 64 + quad * 4 + ms * 16 + r) * 13 + lr] = acc3[ms][r];
    __syncthreads();

    const int base = blockIdx.x * 256;
    int nrows = N - base;
    if (nrows >= 256) {
      // 13312 B per block, 64B-aligned, fully coalesced float4 stores.
      float4* og4 = (float4*)(out + (size_t)base * 13);
      const float4* Ob4 = (const float4*)Obuf;
#pragma unroll
      for (int i = 0; i < 4; ++i) {
        int j = tid + i * 256;
        if (j < 832) og4[j] = Ob4[j];
      }
    } else {
      const int nfl = nrows * 13;
      float* og = out + (size_t)base * 13;
      for (int j = tid; j < nfl; j += 256) og[j] = Obuf[j];
    }
  }
}

// ---------------- host ----------------
extern "C" void kernel_launch(void* const* d_in, const int* in_sizes, int n_in,
                              void* d_out, int out_size, void* d_ws, size_t ws_size,
                              hipStream_t stream) {
  const float* x      = (const float*)d_in[0];
  const float* cr     = (const float*)d_in[1];
  const float* tables = (const float*)d_in[2];
  const float* W1     = (const float*)d_in[3];
  const float* b1     = (const float*)d_in[4];
  const float* W2     = (const float*)d_in[5];
  const float* b2     = (const float*)d_in[6];
  const float* W3     = (const float*)d_in[7];
  const float* b3     = (const float*)d_in[8];
  float* out = (float*)d_out;
  const int N = in_sizes[1];

  // RES with the exact double arithmetic Python uses (bit-identical hashing).
  KParams kp;
  double B = exp((log(16.0 * pow(2.0, 10.0)) - log(16.0)) / 9.0);
  for (int l = 0; l < LVLS; ++l) kp.resf[l] = (float)floor(16.0 * pow(B, (double)l));

  char* ws8 = (char*)d_ws;
  const bool tb = ws_size >= WS_NEEDED;

  const int qblocks = (TAB_ELEMS_F / 4 + 255) / 256;  // 2560: covers table + weights
  if (tb) {
    hipMemsetAsync(ws8 + SC_OFF, 0, 64, stream);
    scale_kernel<<<qblocks, 256, 0, stream>>>(tables, (unsigned*)(ws8 + SC_OFF));
    quant_kernel<<<qblocks, 256, 0, stream>>>(W1, W2, W3, tables, ws8, 1);
  } else {
    quant_kernel<<<(W_ELEMS + 255) / 256, 256, 0, stream>>>(W1, W2, W3, tables, ws8, 0);
  }

  int blocks = (N + 255) / 256;
  if (tb)
    ngp_fused<true><<<blocks, 256, 0, stream>>>(x, cr, tables, ws8, b1, b2, b3, out, N, kp);
  else
    ngp_fused<false><<<blocks, 256, 0, stream>>>(x, cr, tables, ws8, b1, b2, b3, out, N, kp);
}

// Round 2
// 528.062 us; speedup vs baseline: 1.2115x; 1.2115x over previous
//
#include <hip/hip_runtime.h>
#include <cmath>

typedef unsigned int uint32;
typedef __bf16 bf16;
typedef __bf16 bf16x8 __attribute__((ext_vector_type(8)));
typedef float f32x4 __attribute__((ext_vector_type(4)));

#define LVLS 10
#define TSIZE 65536
#define TMASK 65535u
#define PRIME2 2654435761u
#define PRIME3 805459861u

// ---- ws layout (bytes) ----
//   [0,      18432): W1t/W2t/W3t bf16 images (9216 elems)
//   [18432,  18472): dq[10] f32  (scale/127 per level)
//   [18496,  18536): scales[10] u32 (absmax bits, atomicMax target; memset 0)
//   [18560,  18560+2621440): uint8 table [10][65536][4], biased +128 (64B-aligned)
#define WOFF_W1 0
#define WOFF_W2 4096
#define WOFF_W3 8192
#define W_ELEMS 9216
#define DQ_OFF 18432
#define SC_OFF 18496
#define TAB_OFF_B 18560
#define TAB_ELEMS_F (LVLS * TSIZE * 4)   // f32 source elems
#define WS_NEEDED ((size_t)TAB_OFF_B + (size_t)TAB_ELEMS_F)

struct KParams { float resf[LVLS]; };

// ---------------- prep 1: per-level absmax ----------------
__global__ void scale_kernel(const float* __restrict__ tables, unsigned* __restrict__ scales) {
  int tid = blockIdx.x * 256 + threadIdx.x;
  int i4 = tid * 4;
  if (i4 >= TAB_ELEMS_F) return;
  float4 v = *(const float4*)(tables + i4);
  float m = fmaxf(fmaxf(fabsf(v.x), fabsf(v.y)), fmaxf(fabsf(v.z), fabsf(v.w)));
#pragma unroll
  for (int off = 32; off; off >>= 1) m = fmaxf(m, __shfl_xor(m, off, 64));
  if ((threadIdx.x & 63) == 0) {
    int l = i4 >> 18;  // 65536*4 = 2^18 elems per level; waves never straddle
    atomicMax(scales + l, __float_as_uint(m));
  }
}

// ---------------- prep 2: weight transpose + int8 quantize (biased +128) ----------------
__global__ void quant_kernel(const float* __restrict__ W1, const float* __restrict__ W2,
                             const float* __restrict__ W3, const float* __restrict__ tables,
                             char* __restrict__ ws8, int do_tab) {
  int tid = blockIdx.x * 256 + threadIdx.x;
  bf16* wsb = (bf16*)ws8;
  if (tid < W_ELEMS) {
    float v;
    if (tid < 4096) {
      int n = tid >> 6, k = tid & 63;
      v = (k < 40) ? W1[k * 64 + n] : 0.f;
    } else if (tid < 8192) {
      int t2 = tid - 4096; int n = t2 >> 6, k = t2 & 63;
      v = W2[k * 64 + n];
    } else {
      int t3 = tid - 8192; int n = t3 >> 6, k = t3 & 63;
      v = (n < 13) ? W3[k * 13 + n] : 0.f;
    }
    wsb[tid] = (bf16)v;
  }
  const unsigned* scales = (const unsigned*)(ws8 + SC_OFF);
  if (tid < LVLS) {
    float s = __uint_as_float(scales[tid]);
    ((float*)(ws8 + DQ_OFF))[tid] = s * (1.0f / 127.0f);
  }
  if (do_tab) {
    int i4 = tid * 4;
    if (i4 < TAB_ELEMS_F) {
      float4 v = *(const float4*)(tables + i4);
      int l = i4 >> 18;
      float s = __uint_as_float(scales[l]);
      float r = (s > 0.f) ? 127.f / s : 0.f;
      int q0 = (int)rintf(fminf(fmaxf(v.x * r, -127.f), 127.f)) + 128;
      int q1 = (int)rintf(fminf(fmaxf(v.y * r, -127.f), 127.f)) + 128;
      int q2 = (int)rintf(fminf(fmaxf(v.z * r, -127.f), 127.f)) + 128;
      int q3 = (int)rintf(fminf(fmaxf(v.w * r, -127.f), 127.f)) + 128;
      unsigned p = (q0 & 0xff) | ((q1 & 0xff) << 8) | ((q2 & 0xff) << 16) | ((q3 & 0xff) << 24);
      *(unsigned*)(ws8 + TAB_OFF_B + i4) = p;
    }
  }
}

// ---------------- device helpers ----------------
__device__ __forceinline__ float selu_f(float v) {
  float neg = 1.6732632423543772f * (__expf(v) - 1.0f);
  return 1.0507009873554805f * (v > 0.f ? v : neg);
}

// Hbuf: 256 rows x 128 B (stride 64 bf16), XOR-swizzled at 16B granularity so
// 16-lanes-read-16-rows-same-col (GEMM A-operand pattern) is conflict-free.
// (verified: SQ_LDS_BANK_CONFLICT 1.5M -> 0.5M vs stride-72 padding)
__device__ __forceinline__ bf16* hswz(bf16* Hb, int row, int cb) {
  return (bf16*)((char*)Hb + (row << 7) + (cb ^ ((row & 7) << 4)));
}

// One hidden-layer GEMM stage, split into two 32-col halves (lower peak reg
// pressure than the 4x4-acc version). A-fragments are hoisted into registers
// BEFORE any H-write (half 0 writes would otherwise corrupt half 1's A reads,
// since H overwrites the input rows in-place).
__device__ __forceinline__ void gemm_stage(bf16* __restrict__ Hb, int w, int lr, int quad,
                                           const bf16* __restrict__ Bbase,
                                           const float* __restrict__ bvec) {
  bf16x8 Af[2][4];
#pragma unroll
  for (int ks = 0; ks < 2; ++ks)
#pragma unroll
    for (int ms = 0; ms < 4; ++ms)
      Af[ks][ms] = *(const bf16x8*)hswz(Hb, w * 64 + ms * 16 + lr, quad * 16 + ks * 64);
#pragma unroll
  for (int h = 0; h < 2; ++h) {
    f32x4 acc[4][2];
#pragma unroll
    for (int nt2 = 0; nt2 < 2; ++nt2) {
      float b = bvec[(h * 2 + nt2) * 16 + lr];
#pragma unroll
      for (int ms = 0; ms < 4; ++ms) {
        f32x4 a = {b, b, b, b};
        acc[ms][nt2] = a;
      }
    }
#pragma unroll
    for (int ks = 0; ks < 2; ++ks) {
      bf16x8 B0 = *(const bf16x8*)(Bbase + (h * 2 + 0) * 1024 + ks * 32);
      bf16x8 B1 = *(const bf16x8*)(Bbase + (h * 2 + 1) * 1024 + ks * 32);
#pragma unroll
      for (int ms = 0; ms < 4; ++ms) {
        acc[ms][0] = __builtin_amdgcn_mfma_f32_16x16x32_bf16(Af[ks][ms], B0, acc[ms][0], 0, 0, 0);
        acc[ms][1] = __builtin_amdgcn_mfma_f32_16x16x32_bf16(Af[ks][ms], B1, acc[ms][1], 0, 0, 0);
      }
    }
#pragma unroll
    for (int ms = 0; ms < 4; ++ms)
#pragma unroll
      for (int nt2 = 0; nt2 < 2; ++nt2)
#pragma unroll
        for (int r = 0; r < 4; ++r) {
          int row = w * 64 + quad * 4 + ms * 16 + r;
          *hswz(Hb, row, ((h * 2 + nt2) * 16 + lr) * 2) = (bf16)selu_f(acc[ms][nt2][r]);
        }
  }
}

// level offset (l<<16) folded into idx so gathers are a single uniform base.
#define CALC_IDX(L, IDX, F0, F1, F2)                                   \
  do {                                                                 \
    const float rs_ = kp.resf[(L)];                                    \
    float xs_ = px * rs_, ys_ = py * rs_, zs_ = pz * rs_;              \
    float bx_ = floorf(xs_), by_ = floorf(ys_), bz_ = floorf(zs_);     \
    (F0) = xs_ - bx_; (F1) = ys_ - by_; (F2) = zs_ - bz_;              \
    uint32 cx_ = (uint32)bx_, cy_ = (uint32)by_, cz_ = (uint32)bz_;    \
    uint32 hy0_ = cy_ * PRIME2, hy1_ = hy0_ + PRIME2;                  \
    uint32 hz0_ = cz_ * PRIME3, hz1_ = hz0_ + PRIME3;                  \
    uint32 cx1_ = cx_ + 1u;                                            \
    uint32 bse_ = (uint32)(L) << 16;                                   \
    (IDX)[0] = ((cx_ ^ hy0_ ^ hz0_) & TMASK) | bse_;                   \
    (IDX)[1] = ((cx_ ^ hy0_ ^ hz1_) & TMASK) | bse_;                   \
    (IDX)[2] = ((cx_ ^ hy1_ ^ hz0_) & TMASK) | bse_;                   \
    (IDX)[3] = ((cx_ ^ hy1_ ^ hz1_) & TMASK) | bse_;                   \
    (IDX)[4] = ((cx1_ ^ hy0_ ^ hz0_) & TMASK) | bse_;                  \
    (IDX)[5] = ((cx1_ ^ hy0_ ^ hz1_) & TMASK) | bse_;                  \
    (IDX)[6] = ((cx1_ ^ hy1_ ^ hz0_) & TMASK) | bse_;                  \
    (IDX)[7] = ((cx1_ ^ hy1_ ^ hz1_) & TMASK) | bse_;                  \
  } while (0)

// ---------------- fused encode + MLP ----------------
// 256 threads (4 waves), 256 points per block.
// __launch_bounds__(256,4): 128-VGPR budget. (256,5) squeezed to 96 regs and
// spilled feat[]+pipeline to scratch: FETCH 105->410MB, WRITE 156->610MB,
// dur 294->447us, occupancy UNCHANGED (42->43.5). Never re-tighten this.
template <bool TB>
__global__ __launch_bounds__(256, 4)
void ngp_fused(const float* __restrict__ x, const float* __restrict__ cr,
               const float* __restrict__ tables, const char* __restrict__ ws8,
               const float* __restrict__ b1, const float* __restrict__ b2,
               const float* __restrict__ b3, float* __restrict__ out,
               int N, KParams kp) {
  __shared__ __align__(16) bf16 Hbuf[256 * 64];
  const int tid = threadIdx.x;
  const int n = blockIdx.x * 256 + tid;
  const int ncl = (n < N) ? n : 0;

  const float px = x[ncl * 3 + 0];
  const float py = x[ncl * 3 + 1];
  const float pz = x[ncl * 3 + 2];
  const float crv = cr[ncl];
  const float* dq = (const float*)(ws8 + DQ_OFF);

  float feat[40];

  if constexpr (TB) {
    const unsigned* tb = (const unsigned*)(ws8 + TAB_OFF_B);
    // 2-deep software pipeline: issue level l+1's 8 gathers before consuming
    // level l's results -> compiler emits counted vmcnt, VMEM pipe stays fed.
    uint32 idx0[8];
    float pf0, pf1, pf2;
    CALC_IDX(0, idx0, pf0, pf1, pf2);
    unsigned qP[8];
#pragma unroll
    for (int c = 0; c < 8; ++c) qP[c] = tb[idx0[c]];
#pragma unroll
    for (int l = 0; l < LVLS; ++l) {
      unsigned qN[8];
      float nf0 = 0.f, nf1 = 0.f, nf2 = 0.f;
      if (l + 1 < LVLS) {
        uint32 idxN[8];
        CALC_IDX(l + 1, idxN, nf0, nf1, nf2);
#pragma unroll
        for (int c = 0; c < 8; ++c) qN[c] = tb[idxN[c]];
      }
      float fx = pf0, fy = pf1, fz = pf2;
      float wx1 = fx, wx0 = 1.f - fx, wy1 = fy, wy0 = 1.f - fy, wz1 = fz, wz0 = 1.f - fz;
      float wxy00 = wx0 * wy0, wxy01 = wx0 * wy1, wxy10 = wx1 * wy0, wxy11 = wx1 * wy1;
      float w8[8] = {wxy00 * wz0, wxy00 * wz1, wxy01 * wz0, wxy01 * wz1,
                     wxy10 * wz0, wxy10 * wz1, wxy11 * wz0, wxy11 * wz1};
      float a0 = 0.f, a1 = 0.f, a2 = 0.f, a3 = 0.f;
#pragma unroll
      for (int c = 0; c < 8; ++c) {
        // biased-ubyte unpack -> v_cvt_f32_ubyte{0..3}; the -128*sum(w) term
        // folds to -128 exactly (trilinear weights sum to 1).
        unsigned q = qP[c];
        float u0 = (float)(q & 0xffu);
        float u1 = (float)((q >> 8) & 0xffu);
        float u2 = (float)((q >> 16) & 0xffu);
        float u3 = (float)(q >> 24);
        a0 = fmaf(w8[c], u0, a0);
        a1 = fmaf(w8[c], u1, a1);
        a2 = fmaf(w8[c], u2, a2);
        a3 = fmaf(w8[c], u3, a3);
      }
      // l==0: erf(rsqrt(1e-12)) == 1.0f exactly -> skip the transcendental.
      float s = (l == 0) ? dq[0]
                         : erff(rsqrtf(fmaxf(4.0f * (float)l * crv, 1e-12f))) * dq[l];
      feat[0 * 10 + l] = (a0 - 128.f) * s;
      feat[1 * 10 + l] = (a1 - 128.f) * s;
      feat[2 * 10 + l] = (a2 - 128.f) * s;
      feat[3 * 10 + l] = (a3 - 128.f) * s;
      if (l + 1 < LVLS) {
#pragma unroll
        for (int c = 0; c < 8; ++c) qP[c] = qN[c];
        pf0 = nf0; pf1 = nf1; pf2 = nf2;
      }
    }
  } else {
    // f32 fallback (no ws room): unpipelined, matches original semantics.
#pragma unroll
    for (int l = 0; l < LVLS; ++l) {
      uint32 idx[8];
      float fx, fy, fz;
      CALC_IDX(l, idx, fx, fy, fz);
      const float4* tb4 = (const float4*)tables;  // idx already has l<<16 folded
      float f[8][4];
#pragma unroll
      for (int c = 0; c < 8; ++c) {
        float4 q = tb4[idx[c]];
        f[c][0] = q.x; f[c][1] = q.y; f[c][2] = q.z; f[c][3] = q.w;
      }
      float wx1 = fx, wx0 = 1.f - fx, wy1 = fy, wy0 = 1.f - fy, wz1 = fz, wz0 = 1.f - fz;
      float wxy00 = wx0 * wy0, wxy01 = wx0 * wy1, wxy10 = wx1 * wy0, wxy11 = wx1 * wy1;
      float w8[8] = {wxy00 * wz0, wxy00 * wz1, wxy01 * wz0, wxy01 * wz1,
                     wxy10 * wz0, wxy10 * wz1, wxy11 * wz0, wxy11 * wz1};
      float a0 = 0.f, a1 = 0.f, a2 = 0.f, a3 = 0.f;
#pragma unroll
      for (int c = 0; c < 8; ++c) {
        a0 = fmaf(w8[c], f[c][0], a0);
        a1 = fmaf(w8[c], f[c][1], a1);
        a2 = fmaf(w8[c], f[c][2], a2);
        a3 = fmaf(w8[c], f[c][3], a3);
      }
      float s = (l == 0) ? 1.0f : erff(rsqrtf(fmaxf(4.0f * (float)l * crv, 1e-12f)));
      feat[0 * 10 + l] = a0 * s;
      feat[1 * 10 + l] = a1 * s;
      feat[2 * 10 + l] = a2 * s;
      feat[3 * 10 + l] = a3 * s;
    }
  }

  {
#pragma unroll
    for (int c = 0; c < 5; ++c) {
      bf16x8 v;
#pragma unroll
      for (int j = 0; j < 8; ++j) v[j] = (bf16)feat[c * 8 + j];
      *(bf16x8*)hswz(Hbuf, tid, c * 16) = v;
    }
    bf16x8 z;
#pragma unroll
    for (int j = 0; j < 8; ++j) z[j] = (bf16)0.f;
    *(bf16x8*)hswz(Hbuf, tid, 80) = z;
    *(bf16x8*)hswz(Hbuf, tid, 96) = z;
    *(bf16x8*)hswz(Hbuf, tid, 112) = z;
  }
  __syncthreads();

  const int w = tid >> 6;
  const int lane = tid & 63;
  const int lr = lane & 15;
  const int quad = lane >> 4;
  const bf16* wsb = (const bf16*)ws8;

  gemm_stage(Hbuf, w, lr, quad, wsb + WOFF_W1 + lr * 64 + quad * 8, b1);
  __syncthreads();
  gemm_stage(Hbuf, w, lr, quad, wsb + WOFF_W2 + lr * 64 + quad * 8, b2);
  __syncthreads();

  // ---- stage 3 (64 -> 13) + LDS-staged coalesced output ----
  {
    float b3v = (lr < 13) ? b3[lr] : 0.f;
    f32x4 acc3[4];
#pragma unroll
    for (int ms = 0; ms < 4; ++ms) {
      f32x4 a = {b3v, b3v, b3v, b3v};
      acc3[ms] = a;
    }
    const bf16* B3b = wsb + WOFF_W3 + lr * 64 + quad * 8;
    bf16x8 B3[2];
    B3[0] = *(const bf16x8*)(B3b);
    B3[1] = *(const bf16x8*)(B3b + 32);
#pragma unroll
    for (int ks = 0; ks < 2; ++ks) {
      bf16x8 Af[4];
#pragma unroll
      for (int ms = 0; ms < 4; ++ms)
        Af[ms] = *(const bf16x8*)hswz(Hbuf, w * 64 + ms * 16 + lr, quad * 16 + ks * 64);
#pragma unroll
      for (int ms = 0; ms < 4; ++ms)
        acc3[ms] = __builtin_amdgcn_mfma_f32_16x16x32_bf16(Af[ms], B3[ks], acc3[ms], 0, 0, 0);
    }
    __syncthreads();  // done reading Hbuf; reuse it as f32 output stage
    float* Obuf = (float*)Hbuf;  // 256*13*4 = 13312 B <= 32768 B
#pragma unroll
    for (int ms = 0; ms < 4; ++ms)
#pragma unroll
      for (int r = 0; r < 4; ++r)
        if (lr < 13)
          Obuf[(w * 64 + quad * 4 + ms * 16 + r) * 13 + lr] = acc3[ms][r];
    __syncthreads();

    const int base = blockIdx.x * 256;
    int nrows = N - base;
    if (nrows >= 256) {
      // 13312 B per block, 64B-aligned, fully coalesced float4 stores.
      float4* og4 = (float4*)(out + (size_t)base * 13);
      const float4* Ob4 = (const float4*)Obuf;
#pragma unroll
      for (int i = 0; i < 4; ++i) {
        int j = tid + i * 256;
        if (j < 832) og4[j] = Ob4[j];
      }
    } else {
      const int nfl = nrows * 13;
      float* og = out + (size_t)base * 13;
      for (int j = tid; j < nfl; j += 256) og[j] = Obuf[j];
    }
  }
}

// ---------------- host ----------------
extern "C" void kernel_launch(void* const* d_in, const int* in_sizes, int n_in,
                              void* d_out, int out_size, void* d_ws, size_t ws_size,
                              hipStream_t stream) {
  const float* x      = (const float*)d_in[0];
  const float* cr     = (const float*)d_in[1];
  const float* tables = (const float*)d_in[2];
  const float* W1     = (const float*)d_in[3];
  const float* b1     = (const float*)d_in[4];
  const float* W2     = (const float*)d_in[5];
  const float* b2     = (const float*)d_in[6];
  const float* W3     = (const float*)d_in[7];
  const float* b3     = (const float*)d_in[8];
  float* out = (float*)d_out;
  const int N = in_sizes[1];

  // RES with the exact double arithmetic Python uses (bit-identical hashing).
  KParams kp;
  double B = exp((log(16.0 * pow(2.0, 10.0)) - log(16.0)) / 9.0);
  for (int l = 0; l < LVLS; ++l) kp.resf[l] = (float)floor(16.0 * pow(B, (double)l));

  char* ws8 = (char*)d_ws;
  const bool tb = ws_size >= WS_NEEDED;

  const int qblocks = (TAB_ELEMS_F / 4 + 255) / 256;  // 2560: covers table + weights
  if (tb) {
    hipMemsetAsync(ws8 + SC_OFF, 0, 64, stream);
    scale_kernel<<<qblocks, 256, 0, stream>>>(tables, (unsigned*)(ws8 + SC_OFF));
    quant_kernel<<<qblocks, 256, 0, stream>>>(W1, W2, W3, tables, ws8, 1);
  } else {
    quant_kernel<<<(W_ELEMS + 255) / 256, 256, 0, stream>>>(W1, W2, W3, tables, ws8, 0);
  }

  int blocks = (N + 255) / 256;
  if (tb)
    ngp_fused<true><<<blocks, 256, 0, stream>>>(x, cr, tables, ws8, b1, b2, b3, out, N, kp);
  else
    ngp_fused<false><<<blocks, 256, 0, stream>>>(x, cr, tables, ws8, b1, b2, b3, out, N, kp);
}

// Round 3
// 478.205 us; speedup vs baseline: 1.3378x; 1.1043x over previous
//
#include <hip/hip_runtime.h>
#include <cmath>

typedef unsigned int uint32;
typedef __bf16 bf16;
typedef __bf16 bf16x8 __attribute__((ext_vector_type(8)));
typedef float f32x4 __attribute__((ext_vector_type(4)));

#define LVLS 10
#define TSIZE 65536
#define TMASK 65535u
#define PRIME2 2654435761u
#define PRIME3 805459861u

// ---- ws layout (bytes) ----
//   [0,      18432): W1t/W2t/W3t bf16 images (9216 elems)
//                    W1 image input-ordering is PERMUTED: k' = l*4 + d
//                    (matches per-level streamed H-row layout; see encode loop)
//   [18432,  18472): dq[10] f32  (scale/127 per level)
//   [18496,  18536): scales[10] u32 (absmax bits, atomicMax target; memset 0)
//   [18560,  18560+2621440): uint8 table [10][65536][4], biased +128 (64B-aligned)
#define WOFF_W1 0
#define WOFF_W2 4096
#define WOFF_W3 8192
#define W_ELEMS 9216
#define DQ_OFF 18432
#define SC_OFF 18496
#define TAB_OFF_B 18560
#define TAB_ELEMS_F (LVLS * TSIZE * 4)   // f32 source elems
#define WS_NEEDED ((size_t)TAB_OFF_B + (size_t)TAB_ELEMS_F)

struct KParams { float resf[LVLS]; };

// ---------------- prep 1: per-level absmax ----------------
__global__ void scale_kernel(const float* __restrict__ tables, unsigned* __restrict__ scales) {
  int tid = blockIdx.x * 256 + threadIdx.x;
  int i4 = tid * 4;
  if (i4 >= TAB_ELEMS_F) return;
  float4 v = *(const float4*)(tables + i4);
  float m = fmaxf(fmaxf(fabsf(v.x), fabsf(v.y)), fmaxf(fabsf(v.z), fabsf(v.w)));
#pragma unroll
  for (int off = 32; off; off >>= 1) m = fmaxf(m, __shfl_xor(m, off, 64));
  if ((threadIdx.x & 63) == 0) {
    int l = i4 >> 18;  // 65536*4 = 2^18 elems per level; waves never straddle
    atomicMax(scales + l, __float_as_uint(m));
  }
}

// ---------------- prep 2: weight transpose + int8 quantize (biased +128) ----------------
__global__ void quant_kernel(const float* __restrict__ W1, const float* __restrict__ W2,
                             const float* __restrict__ W3, const float* __restrict__ tables,
                             char* __restrict__ ws8, int do_tab) {
  int tid = blockIdx.x * 256 + threadIdx.x;
  bf16* wsb = (bf16*)ws8;
  if (tid < W_ELEMS) {
    float v;
    if (tid < 4096) {
      // W1 image with PERMUTED input index: k' = l*4 + d  <->  k = d*10 + l.
      int n = tid >> 6, kp_ = tid & 63;
      if (kp_ < 40) {
        int l = kp_ >> 2, d = kp_ & 3;
        v = W1[(d * 10 + l) * 64 + n];
      } else v = 0.f;
    } else if (tid < 8192) {
      int t2 = tid - 4096; int n = t2 >> 6, k = t2 & 63;
      v = W2[k * 64 + n];
    } else {
      int t3 = tid - 8192; int n = t3 >> 6, k = t3 & 63;
      v = (n < 13) ? W3[k * 13 + n] : 0.f;
    }
    wsb[tid] = (bf16)v;
  }
  const unsigned* scales = (const unsigned*)(ws8 + SC_OFF);
  if (tid < LVLS) {
    float s = __uint_as_float(scales[tid]);
    ((float*)(ws8 + DQ_OFF))[tid] = s * (1.0f / 127.0f);
  }
  if (do_tab) {
    int i4 = tid * 4;
    if (i4 < TAB_ELEMS_F) {
      float4 v = *(const float4*)(tables + i4);
      int l = i4 >> 18;
      float s = __uint_as_float(scales[l]);
      float r = (s > 0.f) ? 127.f / s : 0.f;
      int q0 = (int)rintf(fminf(fmaxf(v.x * r, -127.f), 127.f)) + 128;
      int q1 = (int)rintf(fminf(fmaxf(v.y * r, -127.f), 127.f)) + 128;
      int q2 = (int)rintf(fminf(fmaxf(v.z * r, -127.f), 127.f)) + 128;
      int q3 = (int)rintf(fminf(fmaxf(v.w * r, -127.f), 127.f)) + 128;
      unsigned p = (q0 & 0xff) | ((q1 & 0xff) << 8) | ((q2 & 0xff) << 16) | ((q3 & 0xff) << 24);
      *(unsigned*)(ws8 + TAB_OFF_B + i4) = p;
    }
  }
}

// ---------------- device helpers ----------------
__device__ __forceinline__ float selu_f(float v) {
  float neg = 1.6732632423543772f * (__expf(v) - 1.0f);
  return 1.0507009873554805f * (v > 0.f ? v : neg);
}

// Hbuf: 256 rows x 128 B (stride 64 bf16), XOR-swizzled at 16B granularity so
// 16-lanes-read-16-rows-same-col (GEMM A-operand pattern) is conflict-free.
// (verified: SQ_LDS_BANK_CONFLICT 1.5M -> 0.5M vs stride-72 padding)
__device__ __forceinline__ bf16* hswz(bf16* Hb, int row, int cb) {
  return (bf16*)((char*)Hb + (row << 7) + (cb ^ ((row & 7) << 4)));
}

// One hidden-layer GEMM stage, split into two 32-col halves (lower peak reg
// pressure than the 4x4-acc version). A-fragments are hoisted into registers
// BEFORE any H-write (half 0 writes would otherwise corrupt half 1's A reads,
// since H overwrites the input rows in-place).
__device__ __forceinline__ void gemm_stage(bf16* __restrict__ Hb, int w, int lr, int quad,
                                           const bf16* __restrict__ Bbase,
                                           const float* __restrict__ bvec) {
  bf16x8 Af[2][4];
#pragma unroll
  for (int ks = 0; ks < 2; ++ks)
#pragma unroll
    for (int ms = 0; ms < 4; ++ms)
      Af[ks][ms] = *(const bf16x8*)hswz(Hb, w * 64 + ms * 16 + lr, quad * 16 + ks * 64);
#pragma unroll
  for (int h = 0; h < 2; ++h) {
    f32x4 acc[4][2];
#pragma unroll
    for (int nt2 = 0; nt2 < 2; ++nt2) {
      float b = bvec[(h * 2 + nt2) * 16 + lr];
#pragma unroll
      for (int ms = 0; ms < 4; ++ms) {
        f32x4 a = {b, b, b, b};
        acc[ms][nt2] = a;
      }
    }
#pragma unroll
    for (int ks = 0; ks < 2; ++ks) {
      bf16x8 B0 = *(const bf16x8*)(Bbase + (h * 2 + 0) * 1024 + ks * 32);
      bf16x8 B1 = *(const bf16x8*)(Bbase + (h * 2 + 1) * 1024 + ks * 32);
#pragma unroll
      for (int ms = 0; ms < 4; ++ms) {
        acc[ms][0] = __builtin_amdgcn_mfma_f32_16x16x32_bf16(Af[ks][ms], B0, acc[ms][0], 0, 0, 0);
        acc[ms][1] = __builtin_amdgcn_mfma_f32_16x16x32_bf16(Af[ks][ms], B1, acc[ms][1], 0, 0, 0);
      }
    }
#pragma unroll
    for (int ms = 0; ms < 4; ++ms)
#pragma unroll
      for (int nt2 = 0; nt2 < 2; ++nt2)
#pragma unroll
        for (int r = 0; r < 4; ++r) {
          int row = w * 64 + quad * 4 + ms * 16 + r;
          *hswz(Hb, row, ((h * 2 + nt2) * 16 + lr) * 2) = (bf16)selu_f(acc[ms][nt2][r]);
        }
  }
}

// level offset (l<<16) folded into idx so gathers are a single uniform base.
#define CALC_IDX(L, IDX, F0, F1, F2)                                   \
  do {                                                                 \
    const float rs_ = kp.resf[(L)];                                    \
    float xs_ = px * rs_, ys_ = py * rs_, zs_ = pz * rs_;              \
    float bx_ = floorf(xs_), by_ = floorf(ys_), bz_ = floorf(zs_);     \
    (F0) = xs_ - bx_; (F1) = ys_ - by_; (F2) = zs_ - bz_;              \
    uint32 cx_ = (uint32)bx_, cy_ = (uint32)by_, cz_ = (uint32)bz_;    \
    uint32 hy0_ = cy_ * PRIME2, hy1_ = hy0_ + PRIME2;                  \
    uint32 hz0_ = cz_ * PRIME3, hz1_ = hz0_ + PRIME3;                  \
    uint32 cx1_ = cx_ + 1u;                                            \
    uint32 bse_ = (uint32)(L) << 16;                                   \
    (IDX)[0] = ((cx_ ^ hy0_ ^ hz0_) & TMASK) | bse_;                   \
    (IDX)[1] = ((cx_ ^ hy0_ ^ hz1_) & TMASK) | bse_;                   \
    (IDX)[2] = ((cx_ ^ hy1_ ^ hz0_) & TMASK) | bse_;                   \
    (IDX)[3] = ((cx_ ^ hy1_ ^ hz1_) & TMASK) | bse_;                   \
    (IDX)[4] = ((cx1_ ^ hy0_ ^ hz0_) & TMASK) | bse_;                  \
    (IDX)[5] = ((cx1_ ^ hy0_ ^ hz1_) & TMASK) | bse_;                  \
    (IDX)[6] = ((cx1_ ^ hy1_ ^ hz0_) & TMASK) | bse_;                  \
    (IDX)[7] = ((cx1_ ^ hy1_ ^ hz1_) & TMASK) | bse_;                  \
  } while (0)

// ---------------- fused encode + MLP ----------------
// 256 threads (4 waves), 256 points per block.
// REGISTER-PRESSURE HISTORY (do not regress):
//  - (256,5) squeeze: alloc pinned at 96, massive spill (FETCH 410MB) r1.
//  - (256,4) + feat[40] + 2-deep pipeline: alloc pinned at 128, ~200B/thread
//    spill (FETCH 216/WRITE 262MB) r2. feat[40] was the structural culprit.
//  - Now: features stream to LDS per level-pair (W1 image permuted to
//    k'=l*4+d), no feat[] array, no explicit pipeline. Peak live state in
//    encode ~ one bf16x8 + gather temps.
template <bool TB>
__global__ __launch_bounds__(256, 4)
void ngp_fused(const float* __restrict__ x, const float* __restrict__ cr,
               const float* __restrict__ tables, const char* __restrict__ ws8,
               const float* __restrict__ b1, const float* __restrict__ b2,
               const float* __restrict__ b3, float* __restrict__ out,
               int N, KParams kp) {
  __shared__ __align__(16) bf16 Hbuf[256 * 64];
  const int tid = threadIdx.x;
  const int n = blockIdx.x * 256 + tid;
  const int ncl = (n < N) ? n : 0;

  const float px = x[ncl * 3 + 0];
  const float py = x[ncl * 3 + 1];
  const float pz = x[ncl * 3 + 2];
  const float crv = cr[ncl];
  const float* dq = (const float*)(ws8 + DQ_OFF);

  // ---- encode: stream one level-pair (8 bf16 = 16 B) to LDS per group ----
#pragma unroll
  for (int g = 0; g < 5; ++g) {
    bf16x8 v;
#pragma unroll
    for (int h = 0; h < 2; ++h) {
      const int l = g * 2 + h;
      uint32 idx[8];
      float fx, fy, fz;
      CALC_IDX(l, idx, fx, fy, fz);
      float a0 = 0.f, a1 = 0.f, a2 = 0.f, a3 = 0.f;
      if constexpr (TB) {
        const unsigned* tb = (const unsigned*)(ws8 + TAB_OFF_B);
        unsigned q[8];
#pragma unroll
        for (int c = 0; c < 8; ++c) q[c] = tb[idx[c]];
        float wx1 = fx, wx0 = 1.f - fx, wy1 = fy, wy0 = 1.f - fy, wz1 = fz, wz0 = 1.f - fz;
        float wxy00 = wx0 * wy0, wxy01 = wx0 * wy1, wxy10 = wx1 * wy0, wxy11 = wx1 * wy1;
        float w8[8] = {wxy00 * wz0, wxy00 * wz1, wxy01 * wz0, wxy01 * wz1,
                       wxy10 * wz0, wxy10 * wz1, wxy11 * wz0, wxy11 * wz1};
#pragma unroll
        for (int c = 0; c < 8; ++c) {
          // biased-ubyte unpack -> v_cvt_f32_ubyte{0..3}; the -128*sum(w) term
          // folds to -128 exactly (trilinear weights sum to 1).
          unsigned q_ = q[c];
          a0 = fmaf(w8[c], (float)(q_ & 0xffu), a0);
          a1 = fmaf(w8[c], (float)((q_ >> 8) & 0xffu), a1);
          a2 = fmaf(w8[c], (float)((q_ >> 16) & 0xffu), a2);
          a3 = fmaf(w8[c], (float)(q_ >> 24), a3);
        }
        // l==0: erf(rsqrt(1e-12)) == 1.0f exactly -> skip the transcendental.
        float s = (l == 0) ? dq[0]
                           : erff(rsqrtf(fmaxf(4.0f * (float)l * crv, 1e-12f))) * dq[l];
        v[h * 4 + 0] = (bf16)((a0 - 128.f) * s);
        v[h * 4 + 1] = (bf16)((a1 - 128.f) * s);
        v[h * 4 + 2] = (bf16)((a2 - 128.f) * s);
        v[h * 4 + 3] = (bf16)((a3 - 128.f) * s);
      } else {
        const float4* tb4 = (const float4*)tables;  // idx already has l<<16 folded
        float f[8][4];
#pragma unroll
        for (int c = 0; c < 8; ++c) {
          float4 q = tb4[idx[c]];
          f[c][0] = q.x; f[c][1] = q.y; f[c][2] = q.z; f[c][3] = q.w;
        }
        float wx1 = fx, wx0 = 1.f - fx, wy1 = fy, wy0 = 1.f - fy, wz1 = fz, wz0 = 1.f - fz;
        float wxy00 = wx0 * wy0, wxy01 = wx0 * wy1, wxy10 = wx1 * wy0, wxy11 = wx1 * wy1;
        float w8[8] = {wxy00 * wz0, wxy00 * wz1, wxy01 * wz0, wxy01 * wz1,
                       wxy10 * wz0, wxy10 * wz1, wxy11 * wz0, wxy11 * wz1};
#pragma unroll
        for (int c = 0; c < 8; ++c) {
          a0 = fmaf(w8[c], f[c][0], a0);
          a1 = fmaf(w8[c], f[c][1], a1);
          a2 = fmaf(w8[c], f[c][2], a2);
          a3 = fmaf(w8[c], f[c][3], a3);
        }
        float s = (l == 0) ? 1.0f : erff(rsqrtf(fmaxf(4.0f * (float)l * crv, 1e-12f)));
        v[h * 4 + 0] = (bf16)(a0 * s);
        v[h * 4 + 1] = (bf16)(a1 * s);
        v[h * 4 + 2] = (bf16)(a2 * s);
        v[h * 4 + 3] = (bf16)(a3 * s);
      }
    }
    *(bf16x8*)hswz(Hbuf, tid, g * 16) = v;
  }
  {
    bf16x8 z;
#pragma unroll
    for (int j = 0; j < 8; ++j) z[j] = (bf16)0.f;
    *(bf16x8*)hswz(Hbuf, tid, 80) = z;
    *(bf16x8*)hswz(Hbuf, tid, 96) = z;
    *(bf16x8*)hswz(Hbuf, tid, 112) = z;
  }
  __syncthreads();

  const int w = tid >> 6;
  const int lane = tid & 63;
  const int lr = lane & 15;
  const int quad = lane >> 4;
  const bf16* wsb = (const bf16*)ws8;

  gemm_stage(Hbuf, w, lr, quad, wsb + WOFF_W1 + lr * 64 + quad * 8, b1);
  __syncthreads();
  gemm_stage(Hbuf, w, lr, quad, wsb + WOFF_W2 + lr * 64 + quad * 8, b2);
  __syncthreads();

  // ---- stage 3 (64 -> 13) + LDS-staged coalesced output ----
  {
    float b3v = (lr < 13) ? b3[lr] : 0.f;
    f32x4 acc3[4];
#pragma unroll
    for (int ms = 0; ms < 4; ++ms) {
      f32x4 a = {b3v, b3v, b3v, b3v};
      acc3[ms] = a;
    }
    const bf16* B3b = wsb + WOFF_W3 + lr * 64 + quad * 8;
    bf16x8 B3[2];
    B3[0] = *(const bf16x8*)(B3b);
    B3[1] = *(const bf16x8*)(B3b + 32);
#pragma unroll
    for (int ks = 0; ks < 2; ++ks) {
      bf16x8 Af[4];
#pragma unroll
      for (int ms = 0; ms < 4; ++ms)
        Af[ms] = *(const bf16x8*)hswz(Hbuf, w * 64 + ms * 16 + lr, quad * 16 + ks * 64);
#pragma unroll
      for (int ms = 0; ms < 4; ++ms)
        acc3[ms] = __builtin_amdgcn_mfma_f32_16x16x32_bf16(Af[ms], B3[ks], acc3[ms], 0, 0, 0);
    }
    __syncthreads();  // done reading Hbuf; reuse it as f32 output stage
    float* Obuf = (float*)Hbuf;  // 256*13*4 = 13312 B <= 32768 B
#pragma unroll
    for (int ms = 0; ms < 4; ++ms)
#pragma unroll
      for (int r = 0; r < 4; ++r)
        if (lr < 13)
          Obuf[(w * 64 + quad * 4 + ms * 16 + r) * 13 + lr] = acc3[ms][r];
    __syncthreads();

    const int base = blockIdx.x * 256;
    int nrows = N - base;
    if (nrows >= 256) {
      // 13312 B per block, 64B-aligned, fully coalesced float4 stores.
      float4* og4 = (float4*)(out + (size_t)base * 13);
      const float4* Ob4 = (const float4*)Obuf;
#pragma unroll
      for (int i = 0; i < 4; ++i) {
        int j = tid + i * 256;
        if (j < 832) og4[j] = Ob4[j];
      }
    } else {
      const int nfl = nrows * 13;
      float* og = out + (size_t)base * 13;
      for (int j = tid; j < nfl; j += 256) og[j] = Obuf[j];
    }
  }
}

// ---------------- host ----------------
extern "C" void kernel_launch(void* const* d_in, const int* in_sizes, int n_in,
                              void* d_out, int out_size, void* d_ws, size_t ws_size,
                              hipStream_t stream) {
  const float* x      = (const float*)d_in[0];
  const float* cr     = (const float*)d_in[1];
  const float* tables = (const float*)d_in[2];
  const float* W1     = (const float*)d_in[3];
  const float* b1     = (const float*)d_in[4];
  const float* W2     = (const float*)d_in[5];
  const float* b2     = (const float*)d_in[6];
  const float* W3     = (const float*)d_in[7];
  const float* b3     = (const float*)d_in[8];
  float* out = (float*)d_out;
  const int N = in_sizes[1];

  // RES with the exact double arithmetic Python uses (bit-identical hashing).
  KParams kp;
  double B = exp((log(16.0 * pow(2.0, 10.0)) - log(16.0)) / 9.0);
  for (int l = 0; l < LVLS; ++l) kp.resf[l] = (float)floor(16.0 * pow(B, (double)l));

  char* ws8 = (char*)d_ws;
  const bool tb = ws_size >= WS_NEEDED;

  const int qblocks = (TAB_ELEMS_F / 4 + 255) / 256;  // 2560: covers table + weights
  if (tb) {
    hipMemsetAsync(ws8 + SC_OFF, 0, 64, stream);
    scale_kernel<<<qblocks, 256, 0, stream>>>(tables, (unsigned*)(ws8 + SC_OFF));
    quant_kernel<<<qblocks, 256, 0, stream>>>(W1, W2, W3, tables, ws8, 1);
  } else {
    quant_kernel<<<(W_ELEMS + 255) / 256, 256, 0, stream>>>(W1, W2, W3, tables, ws8, 0);
  }

  int blocks = (N + 255) / 256;
  if (tb)
    ngp_fused<true><<<blocks, 256, 0, stream>>>(x, cr, tables, ws8, b1, b2, b3, out, N, kp);
  else
    ngp_fused<false><<<blocks, 256, 0, stream>>>(x, cr, tables, ws8, b1, b2, b3, out, N, kp);
}